// Round 10
// baseline (190.789 us; speedup 1.0000x reference)
//
#include <hip/hip_runtime.h>
#include <hip/hip_bf16.h>
#include <stdint.h>

#define DI __device__ __forceinline__

typedef __bf16 bf16x8 __attribute__((ext_vector_type(8)));
typedef __bf16 bf16x4 __attribute__((ext_vector_type(4)));
typedef float f32x4 __attribute__((ext_vector_type(4)));
typedef uint16_t u16x8 __attribute__((ext_vector_type(8)));
typedef uint16_t u16x4 __attribute__((ext_vector_type(4)));
typedef uint32_t u32x2 __attribute__((ext_vector_type(2)));

// ---------- helpers ----------
DI uint16_t f2bf(float f) {
    union { float f; uint32_t u; } v; v.f = f;
    return (uint16_t)((v.u + 0x7fffu + ((v.u >> 16) & 1u)) >> 16);
}

DI void gload_lds16(const void* g, void* l) {
    __builtin_amdgcn_global_load_lds(
        (const __attribute__((address_space(1))) uint32_t*)g,
        (__attribute__((address_space(3))) uint32_t*)l, 16, 0, 0);
}

// stage a 64x64 bf16 tile (row pitch `pitch` elems) into LDS, linear dest,
// inverse-XOR-swizzled source so reads use byte ^= (row&7)<<4.
DI void stage64_swz(const uint16_t* gbase, int pitch, uint16_t* lds, int tid) {
#pragma unroll
    for (int s = 0; s < 2; ++s) {
        int off  = s * 4096 + tid * 16;     // byte offset in LDS
        int row  = off >> 7;                // 128 B per row
        int slot = (off >> 4) & 7;          // 16 B slot within row
        const uint16_t* gp = gbase + (size_t)row * pitch + ((slot ^ (row & 7)) << 3);
        gload_lds16(gp, (char*)lds + off);
    }
}

// swizzled fragment read: row-major [64][64] bf16 tile, returns 8 bf16 at
// (row, elem ch*32 + g*8 .. +7)
DI bf16x8 ldsfrag(const uint16_t* lds, int row, int ch, int g) {
    int bc = (ch * 64 + g * 16) ^ ((row & 7) << 4);
    return *(const bf16x8*)((const char*)lds + row * 128 + bc);
}

// transpose 64x64 f32->bf16 tile through LDS (used by merged prep kernel)
DI void transpose_tile(const float* __restrict__ in, uint16_t* __restrict__ out,
                       int R, int Cc, int c0, int r0, int tid,
                       uint16_t (*tl)[66]) {
    int rl = tid >> 2, cch = tid & 3;
#pragma unroll
    for (int j = 0; j < 4; ++j) {
        float4 v = *(const float4*)(in + (size_t)(r0 + rl) * Cc + c0 + cch * 16 + j * 4);
        int cb = cch * 16 + j * 4;
        tl[cb + 0][rl] = f2bf(v.x);
        tl[cb + 1][rl] = f2bf(v.y);
        tl[cb + 2][rl] = f2bf(v.z);
        tl[cb + 3][rl] = f2bf(v.w);
    }
    __syncthreads();
    int cl = tid >> 2, rch = tid & 3;
    u16x8 o0, o1;
#pragma unroll
    for (int e = 0; e < 8; ++e) { o0[e] = tl[cl][rch * 16 + e]; o1[e] = tl[cl][rch * 16 + 8 + e]; }
    uint16_t* op = out + (size_t)(c0 + cl) * R + r0 + rch * 16;
    *(u16x8*)op = o0;
    *(u16x8*)(op + 8) = o1;
}

// ---------- merged prep: x cast + Wqkv^T + Wo^T + counter zeroing ----------
__global__ __launch_bounds__(256) void k_prep(const float* __restrict__ x,
                                              uint16_t* __restrict__ xbf,
                                              const float* __restrict__ Wqkv,
                                              uint16_t* __restrict__ WqkvT,
                                              const float* __restrict__ Wo,
                                              uint16_t* __restrict__ WoT,
                                              int* __restrict__ counters) {
    __shared__ uint16_t tl[64][66];
    int b = blockIdx.x, tid = threadIdx.x;
    if (b == 0 && tid < 16) counters[tid] = 0;
    if (b < 1536) {
        int i = b * 256 + tid;
        const float4* p = (const float4*)x + (size_t)i * 2;
        float4 a = p[0], c = p[1];
        u16x8 o;
        o[0] = f2bf(a.x); o[1] = f2bf(a.y); o[2] = f2bf(a.z); o[3] = f2bf(a.w);
        o[4] = f2bf(c.x); o[5] = f2bf(c.y); o[6] = f2bf(c.z); o[7] = f2bf(c.w);
        *(u16x8*)(xbf + (size_t)i * 8) = o;
    } else if (b < 1968) {
        int bb = b - 1536;                  // 36 x 12 tiles, Cc = 2304
        transpose_tile(Wqkv, WqkvT, 768, 2304, (bb % 36) * 64, (bb / 36) * 64, tid, tl);
    } else {
        int bb = b - 1968;                  // 12 x 12 tiles, Cc = 768
        transpose_tile(Wo, WoT, 768, 768, (bb % 12) * 64, (bb / 12) * 64, tid, tl);
    }
}

// ---------- bf16 MFMA GEMM, 2-phase double-buffered ----------
// Per k-iter: stage(next tile -> buf^1) issued FIRST, then ds_read+MFMA on buf,
// then vmcnt(0)+barrier (prefetch latency hidden under compute). 1 barrier/iter.
// MODE 0: QKV epilogue (Q,K scatter, V direct-transposed); MODE 1: f32 out+bias.
template <int BM, int BN, int MODE>
__global__ __launch_bounds__(256) void k_gemm(const uint16_t* __restrict__ A,
                                              const uint16_t* __restrict__ Bm,
                                              const float* __restrict__ bias,
                                              float* __restrict__ Cout,
                                              uint16_t* __restrict__ q_ws,
                                              uint16_t* __restrict__ k_ws,
                                              uint16_t* __restrict__ vt_ws,
                                              int Ndim, int Kdim) {
    __shared__ uint16_t Al[2][BM * 64];
    __shared__ uint16_t Bl[2][BN * 64];
    constexpr int WM = BM / 2, WN = BN / 2, MI = WM / 16, NJ = WN / 16;
    constexpr int AS = BM * 128 / 4096, BS = BN * 128 / 4096;
    int tid = threadIdx.x;
    int wave = tid >> 6, lane = tid & 63, g = lane >> 4, cc = lane & 15;
    int nwgx = gridDim.x;
    int id = blockIdx.y * nwgx + blockIdx.x;
    int chunk = (nwgx * gridDim.y) >> 3;
    id = (id & 7) * chunk + (id >> 3);
    int bm = (id / nwgx) * BM, bn = (id % nwgx) * BN;
    int wr = (wave >> 1) * WM, wc = (wave & 1) * WN;
    f32x4 acc[MI][NJ] = {};

    // prologue: stage kt=0 into buffer 0
#pragma unroll
    for (int s = 0; s < AS; ++s) {
        int off = s * 4096 + tid * 16;
        int row = off >> 7, slot = (off >> 4) & 7;
        gload_lds16(A + (size_t)(bm + row) * Kdim + slot * 8, (char*)Al[0] + off);
    }
#pragma unroll
    for (int s = 0; s < BS; ++s) {
        int off = s * 4096 + tid * 16;
        int row = off >> 7, slot = (off >> 4) & 7;
        gload_lds16(Bm + (size_t)(bn + row) * Kdim + slot * 8, (char*)Bl[0] + off);
    }
    asm volatile("s_waitcnt vmcnt(0)" ::: "memory");
    __builtin_amdgcn_s_barrier();

    int cur = 0;
    for (int kt = 0; kt < Kdim; kt += 64) {
        if (kt + 64 < Kdim) {
#pragma unroll
            for (int s = 0; s < AS; ++s) {
                int off = s * 4096 + tid * 16;
                int row = off >> 7, slot = (off >> 4) & 7;
                gload_lds16(A + (size_t)(bm + row) * Kdim + kt + 64 + slot * 8,
                            (char*)Al[cur ^ 1] + off);
            }
#pragma unroll
            for (int s = 0; s < BS; ++s) {
                int off = s * 4096 + tid * 16;
                int row = off >> 7, slot = (off >> 4) & 7;
                gload_lds16(Bm + (size_t)(bn + row) * Kdim + kt + 64 + slot * 8,
                            (char*)Bl[cur ^ 1] + off);
            }
        }
        __builtin_amdgcn_sched_barrier(0);
        bf16x8 af[MI][2], bfr[NJ][2];
#pragma unroll
        for (int mi = 0; mi < MI; ++mi)
#pragma unroll
            for (int ch = 0; ch < 2; ++ch)
                af[mi][ch] = *(const bf16x8*)((const char*)Al[cur] + (wr + mi * 16 + cc) * 128 + ch * 64 + g * 16);
#pragma unroll
        for (int nj = 0; nj < NJ; ++nj)
#pragma unroll
            for (int ch = 0; ch < 2; ++ch)
                bfr[nj][ch] = *(const bf16x8*)((const char*)Bl[cur] + (wc + nj * 16 + cc) * 128 + ch * 64 + g * 16);
        __builtin_amdgcn_s_setprio(1);
#pragma unroll
        for (int mi = 0; mi < MI; ++mi)
#pragma unroll
            for (int nj = 0; nj < NJ; ++nj) {
                acc[mi][nj] = __builtin_amdgcn_mfma_f32_16x16x32_bf16(af[mi][0], bfr[nj][0], acc[mi][nj], 0, 0, 0);
                acc[mi][nj] = __builtin_amdgcn_mfma_f32_16x16x32_bf16(af[mi][1], bfr[nj][1], acc[mi][nj], 0, 0, 0);
            }
        __builtin_amdgcn_s_setprio(0);
        // drain the prefetch (overlapped with the MFMA above), sync, swap
        asm volatile("s_waitcnt vmcnt(0)" ::: "memory");
        __builtin_amdgcn_s_barrier();
        cur ^= 1;
    }

#pragma unroll
    for (int mi = 0; mi < MI; ++mi)
#pragma unroll
        for (int nj = 0; nj < NJ; ++nj) {
            int n = bn + wc + nj * 16 + cc;
            float bv = bias[n];
            if (MODE == 0) {
                int which = (n >= 1536) ? 2 : (n >= 768 ? 1 : 0);
                int cn = n - which * 768;
                int h = cn >> 6, dd = cn & 63;
                int t0 = bm + wr + mi * 16 + 4 * g;     // 4 consecutive rows (same b)
                int b = t0 >> 11, t = t0 & 2047;
                int bh = b * 12 + h;
                if (which == 2) {
                    u16x4 pv;
#pragma unroll
                    for (int r = 0; r < 4; ++r) pv[r] = f2bf(acc[mi][nj][r] + bv);
                    *(u16x4*)(vt_ws + ((size_t)bh * 64 + dd) * 2048 + t) = pv;
                } else {
                    uint16_t* dst = (which == 0) ? q_ws : k_ws;
                    float scale = (which == 0) ? 0.125f : 1.0f;
#pragma unroll
                    for (int r = 0; r < 4; ++r)
                        dst[((size_t)bh * 2048 + t + r) * 64 + dd] = f2bf((acc[mi][nj][r] + bv) * scale);
                }
            } else {
#pragma unroll
                for (int r = 0; r < 4; ++r) {
                    int m = bm + wr + mi * 16 + 4 * g + r;
                    Cout[(size_t)m * Ndim + n] = acc[mi][nj][r] + bv;
                }
            }
        }
}

// ---------- fused causal attention (R8 structure: plain full-line stores) ----------
__global__ __launch_bounds__(256) void k_attn10(const uint16_t* __restrict__ Q,
                                                const uint16_t* __restrict__ K,
                                                const uint16_t* __restrict__ VT,
                                                float* __restrict__ attn,
                                                uint16_t* __restrict__ O,
                                                int* __restrict__ counters) {
    __shared__ uint16_t Kl[2][64 * 64];
    __shared__ uint16_t Vl[2][64 * 64];
    __shared__ uint16_t Pl[64 * 64];
    __shared__ int s_unit;
    int tid = threadIdx.x;
    int wave = tid >> 6, lane = tid & 63, g = lane >> 4, cc = lane & 15;
    int qx = blockIdx.x & 7;                 // XCD heuristic (round-robin dispatch)

    for (;;) {
        __syncthreads();
        if (tid == 0) s_unit = atomicAdd(&counters[qx], 1);
        __syncthreads();
        int u = s_unit;
        if (u >= 96) break;
        int qt = 31 - (u / 3);               // heaviest first
        int bh = qx * 3 + (u % 3);
        int qb = qt * 64, nt = qt + 1;
        const uint16_t* Qp = Q + (size_t)bh * 2048 * 64;
        const uint16_t* Kp = K + (size_t)bh * 2048 * 64;
        const uint16_t* Vp = VT + (size_t)bh * 64 * 2048;
        float* ap = attn + (size_t)bh * 2048 * 2048 + (size_t)qb * 2048;

        const uint16_t* qrp = Qp + (size_t)(qb + 16 * wave + cc) * 64 + g * 8;
        bf16x8 qa0 = *(const bf16x8*)qrp;
        bf16x8 qa1 = *(const bf16x8*)(qrp + 32);
        int myq = qb + 16 * wave + cc;
        int prow = 16 * wave + cc;

        // ---- pass 1: row sums (K-only) ----
        float lpart = 0.f;
        stage64_swz(Kp, 64, Kl[0], tid);
        asm volatile("s_waitcnt vmcnt(0)" ::: "memory");
        __builtin_amdgcn_s_barrier();
        int cur = 0;
        for (int ks = 0; ks < nt; ++ks) {
            if (ks + 1 < nt) stage64_swz(Kp + (size_t)(ks + 1) * 4096, 64, Kl[cur ^ 1], tid);
            __builtin_amdgcn_sched_barrier(0);
#pragma unroll
            for (int t = 0; t < 4; ++t) {
                bf16x8 k0 = ldsfrag(Kl[cur], t * 16 + cc, 0, g);
                bf16x8 k1 = ldsfrag(Kl[cur], t * 16 + cc, 1, g);
                f32x4 z = {0.f, 0.f, 0.f, 0.f};
                __builtin_amdgcn_s_setprio(1);
                z = __builtin_amdgcn_mfma_f32_16x16x32_bf16(k0, qa0, z, 0, 0, 0);
                z = __builtin_amdgcn_mfma_f32_16x16x32_bf16(k1, qa1, z, 0, 0, 0);
                __builtin_amdgcn_s_setprio(0);
#pragma unroll
                for (int r = 0; r < 4; ++r) {
                    int kabs = ks * 64 + t * 16 + 4 * g + r;
                    lpart += (kabs <= myq) ? __expf(z[r]) : 0.f;
                }
            }
            asm volatile("s_waitcnt vmcnt(0)" ::: "memory");
            __builtin_amdgcn_s_barrier();
            cur ^= 1;
        }
        lpart += __shfl_xor(lpart, 16, 64);
        lpart += __shfl_xor(lpart, 32, 64);
        float rinv = 1.0f / lpart;

        // ---- pass 2: P -> LDS -> PV, then full-line attn dump ----
        f32x4 Oa[4] = {};
        stage64_swz(Kp, 64, Kl[0], tid);
        stage64_swz(Vp, 2048, Vl[0], tid);
        asm volatile("s_waitcnt vmcnt(0)" ::: "memory");
        __builtin_amdgcn_s_barrier();
        cur = 0;
        for (int ks = 0; ks < nt; ++ks) {
            if (ks + 1 < nt) {
                stage64_swz(Kp + (size_t)(ks + 1) * 4096, 64, Kl[cur ^ 1], tid);
                stage64_swz(Vp + (size_t)(ks + 1) * 64, 2048, Vl[cur ^ 1], tid);
            }
            __builtin_amdgcn_sched_barrier(0);
#pragma unroll
            for (int t = 0; t < 4; ++t) {
                bf16x8 k0 = ldsfrag(Kl[cur], t * 16 + cc, 0, g);
                bf16x8 k1 = ldsfrag(Kl[cur], t * 16 + cc, 1, g);
                f32x4 z = {0.f, 0.f, 0.f, 0.f};
                __builtin_amdgcn_s_setprio(1);
                z = __builtin_amdgcn_mfma_f32_16x16x32_bf16(k0, qa0, z, 0, 0, 0);
                z = __builtin_amdgcn_mfma_f32_16x16x32_bf16(k1, qa1, z, 0, 0, 0);
                __builtin_amdgcn_s_setprio(0);
                bf16x4 pb;
#pragma unroll
                for (int r = 0; r < 4; ++r) {
                    int kabs = ks * 64 + t * 16 + 4 * g + r;
                    float p = (kabs <= myq) ? __expf(z[r]) * rinv : 0.f;
                    pb[r] = (__bf16)p;
                }
                *(bf16x4*)((char*)Pl + prow * 128 + ((t * 32 + 8 * g) ^ ((prow & 7) << 4))) = pb;
            }
            // P round-trip fence (wave-private rows; DS in-order per wave)
            asm volatile("s_waitcnt lgkmcnt(0)" ::: "memory");
            __builtin_amdgcn_sched_barrier(0);
            bf16x8 pa0 = ldsfrag(Pl, prow, 0, g);
            bf16x8 pa1 = ldsfrag(Pl, prow, 1, g);
            __builtin_amdgcn_s_setprio(1);
#pragma unroll
            for (int n = 0; n < 4; ++n) {
                bf16x8 v0 = ldsfrag(Vl[cur], n * 16 + cc, 0, g);
                bf16x8 v1 = ldsfrag(Vl[cur], n * 16 + cc, 1, g);
                Oa[n] = __builtin_amdgcn_mfma_f32_16x16x32_bf16(pa0, v0, Oa[n], 0, 0, 0);
                Oa[n] = __builtin_amdgcn_mfma_f32_16x16x32_bf16(pa1, v1, Oa[n], 0, 0, 0);
            }
            __builtin_amdgcn_s_setprio(0);
            // attn dump from Pl: per inst = 4 rows x 256B contiguous (full lines)
#pragma unroll
            for (int i = 0; i < 4; ++i) {
                int row = 16 * wave + i * 4 + (lane >> 4);
                int bcol = (lane & 15) * 8;
                u32x2 w = *(const u32x2*)((const char*)Pl + row * 128 + (bcol ^ ((row & 7) << 4)));
                union { uint32_t u; float f; } a0, a1, a2, a3;
                a0.u = w[0] << 16; a1.u = w[0] & 0xFFFF0000u;
                a2.u = w[1] << 16; a3.u = w[1] & 0xFFFF0000u;
                f32x4 ov = {a0.f, a1.f, a2.f, a3.f};
                *(f32x4*)(ap + (size_t)row * 2048 + ks * 64 + (lane & 15) * 4) = ov;
            }
            // counted wait: drains the 4 stage loads, attn stores stay in flight
            asm volatile("s_waitcnt vmcnt(4)" ::: "memory");
            __builtin_amdgcn_s_barrier();
            cur ^= 1;
        }

        // zero-fill upper triangle: 1KB-contiguous per wave-inst
        {
            f32x4 zz = {0.f, 0.f, 0.f, 0.f};
            int zb = nt * 64;
            for (int r = 0; r < 16; ++r) {
                float* zp = ap + (size_t)(16 * wave + r) * 2048;
                for (int c = zb + lane * 4; c < 2048; c += 256)
                    *(f32x4*)(zp + c) = zz;
            }
        }

        // O epilogue (P pre-normalized -> Oa already normalized)
        int b = bh / 12, h = bh % 12;
#pragma unroll
        for (int n = 0; n < 4; ++n)
#pragma unroll
            for (int r = 0; r < 4; ++r) {
                int mrow = b * 2048 + qb + 16 * wave + 4 * g + r;
                int col = h * 64 + n * 16 + cc;
                O[(size_t)mrow * 768 + col] = f2bf(Oa[n][r]);
            }
    }
}

// ---------- launcher ----------
extern "C" void kernel_launch(void* const* d_in, const int* in_sizes, int n_in,
                              void* d_out, int out_size, void* d_ws, size_t ws_size,
                              hipStream_t stream) {
    (void)in_sizes; (void)n_in; (void)out_size; (void)ws_size;
    const float* x    = (const float*)d_in[0];
    const float* Wqkv = (const float*)d_in[1];
    const float* bqkv = (const float*)d_in[2];
    const float* Wo   = (const float*)d_in[3];
    const float* bo   = (const float*)d_in[4];
    float* out  = (float*)d_out;
    float* attn = out + (size_t)4096 * 768;

    char* ws = (char*)d_ws;
    uint16_t* xbf   = (uint16_t*)(ws);             // 4096x768 bf16 (reused as Ow)
    uint16_t* WqkvT = (uint16_t*)(ws + 6291456);   // 2304x768 bf16
    uint16_t* WoT   = (uint16_t*)(ws + 9830400);   // 768x768 bf16
    uint16_t* Qw    = (uint16_t*)(ws + 11010048);  // [24][2048][64]
    uint16_t* Kw    = (uint16_t*)(ws + 17301504);  // [24][2048][64]
    uint16_t* VTw   = (uint16_t*)(ws + 29884416);  // [24][64][2048]
    int* counters   = (int*)(ws + 36175872);       // per-XCD work counters
    uint16_t* Ow    = xbf;                         // xbf dead after QKV GEMM

    k_prep<<<dim3(2112), 256, 0, stream>>>(x, xbf, Wqkv, WqkvT, Wo, WoT, counters);
    k_gemm<128, 128, 0><<<dim3(18, 32), 256, 0, stream>>>(xbf, WqkvT, bqkv, nullptr,
                                                          Qw, Kw, VTw, 2304, 768);
    k_attn10<<<dim3(1024), 256, 0, stream>>>(Qw, Kw, VTw, attn, Ow, counters);
    k_gemm<64, 128, 1><<<dim3(6, 64), 256, 0, stream>>>(Ow, WoT, bo, out,
                                                        nullptr, nullptr, nullptr, 768, 768);
}

// Round 11
// 179.216 us; speedup vs baseline: 1.0646x; 1.0646x over previous
//
#include <hip/hip_runtime.h>
#include <hip/hip_bf16.h>
#include <stdint.h>

#define DI __device__ __forceinline__

typedef __bf16 bf16x8 __attribute__((ext_vector_type(8)));
typedef __bf16 bf16x4 __attribute__((ext_vector_type(4)));
typedef float f32x4 __attribute__((ext_vector_type(4)));
typedef uint16_t u16x8 __attribute__((ext_vector_type(8)));
typedef uint32_t u32x2 __attribute__((ext_vector_type(2)));

// ---------- helpers ----------
DI uint16_t f2bf(float f) {
    union { float f; uint32_t u; } v; v.f = f;
    return (uint16_t)((v.u + 0x7fffu + ((v.u >> 16) & 1u)) >> 16);
}

DI void gload_lds16(const void* g, void* l) {
    __builtin_amdgcn_global_load_lds(
        (const __attribute__((address_space(1))) uint32_t*)g,
        (__attribute__((address_space(3))) uint32_t*)l, 16, 0, 0);
}

// stage a 64x64 bf16 tile (row pitch `pitch` elems) into LDS, linear dest,
// inverse-XOR-swizzled source so reads use byte ^= (row&7)<<4.
DI void stage64_swz(const uint16_t* gbase, int pitch, uint16_t* lds, int tid) {
#pragma unroll
    for (int s = 0; s < 2; ++s) {
        int off  = s * 4096 + tid * 16;     // byte offset in LDS
        int row  = off >> 7;                // 128 B per row
        int slot = (off >> 4) & 7;          // 16 B slot within row
        const uint16_t* gp = gbase + (size_t)row * pitch + ((slot ^ (row & 7)) << 3);
        gload_lds16(gp, (char*)lds + off);
    }
}

// swizzled fragment read: row-major [64][64] bf16 tile, returns 8 bf16 at
// (row, elem ch*32 + g*8 .. +7)
DI bf16x8 ldsfrag(const uint16_t* lds, int row, int ch, int g) {
    int bc = (ch * 64 + g * 16) ^ ((row & 7) << 4);
    return *(const bf16x8*)((const char*)lds + row * 128 + bc);
}

// transpose 64x64 f32->bf16 tile through LDS (used by merged prep kernel)
DI void transpose_tile(const float* __restrict__ in, uint16_t* __restrict__ out,
                       int R, int Cc, int c0, int r0, int tid,
                       uint16_t (*tl)[66]) {
    int rl = tid >> 2, cch = tid & 3;
#pragma unroll
    for (int j = 0; j < 4; ++j) {
        float4 v = *(const float4*)(in + (size_t)(r0 + rl) * Cc + c0 + cch * 16 + j * 4);
        int cb = cch * 16 + j * 4;
        tl[cb + 0][rl] = f2bf(v.x);
        tl[cb + 1][rl] = f2bf(v.y);
        tl[cb + 2][rl] = f2bf(v.z);
        tl[cb + 3][rl] = f2bf(v.w);
    }
    __syncthreads();
    int cl = tid >> 2, rch = tid & 3;
    u16x8 o0, o1;
#pragma unroll
    for (int e = 0; e < 8; ++e) { o0[e] = tl[cl][rch * 16 + e]; o1[e] = tl[cl][rch * 16 + 8 + e]; }
    uint16_t* op = out + (size_t)(c0 + cl) * R + r0 + rch * 16;
    *(u16x8*)op = o0;
    *(u16x8*)(op + 8) = o1;
}

// ---------- merged prep: x cast + Wqkv^T + Wo^T + counter zeroing ----------
__global__ __launch_bounds__(256) void k_prep(const float* __restrict__ x,
                                              uint16_t* __restrict__ xbf,
                                              const float* __restrict__ Wqkv,
                                              uint16_t* __restrict__ WqkvT,
                                              const float* __restrict__ Wo,
                                              uint16_t* __restrict__ WoT,
                                              int* __restrict__ counters) {
    __shared__ uint16_t tl[64][66];
    int b = blockIdx.x, tid = threadIdx.x;
    if (b == 0 && tid < 16) counters[tid] = 0;
    if (b < 1536) {
        int i = b * 256 + tid;
        const float4* p = (const float4*)x + (size_t)i * 2;
        float4 a = p[0], c = p[1];
        u16x8 o;
        o[0] = f2bf(a.x); o[1] = f2bf(a.y); o[2] = f2bf(a.z); o[3] = f2bf(a.w);
        o[4] = f2bf(c.x); o[5] = f2bf(c.y); o[6] = f2bf(c.z); o[7] = f2bf(c.w);
        *(u16x8*)(xbf + (size_t)i * 8) = o;
    } else if (b < 1968) {
        int bb = b - 1536;                  // 36 x 12 tiles, Cc = 2304
        transpose_tile(Wqkv, WqkvT, 768, 2304, (bb % 36) * 64, (bb / 36) * 64, tid, tl);
    } else {
        int bb = b - 1968;                  // 12 x 12 tiles, Cc = 768
        transpose_tile(Wo, WoT, 768, 768, (bb % 12) * 64, (bb / 12) * 64, tid, tl);
    }
}

// ---------- bf16 MFMA GEMM (single-buffered, R8 loop) ----------
// MODE 0 (BM=BN=128): epilogue routed through the dead staging LDS ->
//   Q/K: SH[m][n] then full-line [t][d] dumps; V: SH[n][m] then [d][t] dumps.
// MODE 1: plain f32 out + bias (direct stores).
template <int BM, int BN, int MODE>
__global__ __launch_bounds__(256) void k_gemm(const uint16_t* __restrict__ A,
                                              const uint16_t* __restrict__ Bm,
                                              const float* __restrict__ bias,
                                              float* __restrict__ Cout,
                                              uint16_t* __restrict__ q_ws,
                                              uint16_t* __restrict__ k_ws,
                                              uint16_t* __restrict__ vt_ws,
                                              int Ndim, int Kdim) {
    __shared__ uint16_t SH[(BM + BN) * 64];
    uint16_t* Al = SH;
    uint16_t* Bl = SH + BM * 64;
    constexpr int WM = BM / 2, WN = BN / 2, MI = WM / 16, NJ = WN / 16;
    constexpr int AS = BM * 128 / 4096, BS = BN * 128 / 4096;
    int tid = threadIdx.x;
    int wave = tid >> 6, lane = tid & 63, g = lane >> 4, cc = lane & 15;
    int nwgx = gridDim.x;
    int id = blockIdx.y * nwgx + blockIdx.x;
    int chunk = (nwgx * gridDim.y) >> 3;
    id = (id & 7) * chunk + (id >> 3);
    int bm = (id / nwgx) * BM, bn = (id % nwgx) * BN;
    int wr = (wave >> 1) * WM, wc = (wave & 1) * WN;
    f32x4 acc[MI][NJ] = {};

    for (int kt = 0; kt < Kdim; kt += 64) {
        __syncthreads();
#pragma unroll
        for (int s = 0; s < AS; ++s) {
            int off = s * 4096 + tid * 16;
            int row = off >> 7, slot = (off >> 4) & 7;
            gload_lds16(A + (size_t)(bm + row) * Kdim + kt + slot * 8, (char*)Al + off);
        }
#pragma unroll
        for (int s = 0; s < BS; ++s) {
            int off = s * 4096 + tid * 16;
            int row = off >> 7, slot = (off >> 4) & 7;
            gload_lds16(Bm + (size_t)(bn + row) * Kdim + kt + slot * 8, (char*)Bl + off);
        }
        __syncthreads();
        bf16x8 af[MI][2], bfr[NJ][2];
#pragma unroll
        for (int mi = 0; mi < MI; ++mi)
#pragma unroll
            for (int ch = 0; ch < 2; ++ch)
                af[mi][ch] = *(const bf16x8*)((const char*)Al + (wr + mi * 16 + cc) * 128 + ch * 64 + g * 16);
#pragma unroll
        for (int nj = 0; nj < NJ; ++nj)
#pragma unroll
            for (int ch = 0; ch < 2; ++ch)
                bfr[nj][ch] = *(const bf16x8*)((const char*)Bl + (wc + nj * 16 + cc) * 128 + ch * 64 + g * 16);
        __builtin_amdgcn_s_setprio(1);
#pragma unroll
        for (int mi = 0; mi < MI; ++mi)
#pragma unroll
            for (int nj = 0; nj < NJ; ++nj) {
                acc[mi][nj] = __builtin_amdgcn_mfma_f32_16x16x32_bf16(af[mi][0], bfr[nj][0], acc[mi][nj], 0, 0, 0);
                acc[mi][nj] = __builtin_amdgcn_mfma_f32_16x16x32_bf16(af[mi][1], bfr[nj][1], acc[mi][nj], 0, 0, 0);
            }
        __builtin_amdgcn_s_setprio(0);
    }

    if (MODE == 0) {
        // ---- LDS-routed epilogue (BM=BN=128; SH = 16384 elems = BM*BN) ----
        int which = (bn >= 1536) ? 2 : (bn >= 768 ? 1 : 0);
        int h0 = (bn - which * 768) >> 6;   // first of the 2 heads this block covers
        int b = bm >> 11;                   // uniform (2048 % 128 == 0)
        int tb = bm & 2047;
        float scale = (which == 0) ? 0.125f : 1.0f;
        __syncthreads();                    // staging reads done before overwrite
#pragma unroll
        for (int mi = 0; mi < MI; ++mi)
#pragma unroll
            for (int nj = 0; nj < NJ; ++nj) {
                int nl = wc + nj * 16 + cc;
                float bv = bias[bn + nl];
#pragma unroll
                for (int r = 0; r < 4; ++r) {
                    int ml = wr + mi * 16 + 4 * g + r;
                    uint16_t v = f2bf((acc[mi][nj][r] + bv) * scale);
                    if (which == 2) SH[nl * 128 + ml] = v;   // V: [n][m] (transposed)
                    else            SH[ml * 128 + nl] = v;   // Q/K: [m][n]
                }
            }
        __syncthreads();
        uint16_t* dst0 = (which == 0) ? q_ws : k_ws;
#pragma unroll
        for (int it = 0; it < 8; ++it) {
            int idx = it * 2048 + tid * 8;
            u16x8 v = *(const u16x8*)(SH + idx);
            int rowl = idx >> 7, coll = idx & 127;
            if (which == 2) {
                int h = h0 + (rowl >> 6), dd = rowl & 63;
                *(u16x8*)(vt_ws + ((size_t)(b * 12 + h) * 64 + dd) * 2048 + tb + coll) = v;
            } else {
                int h = h0 + (coll >> 6), dd = coll & 63;
                *(u16x8*)(dst0 + ((size_t)(b * 12 + h) * 2048 + tb + rowl) * 64 + dd) = v;
            }
        }
    } else {
#pragma unroll
        for (int mi = 0; mi < MI; ++mi)
#pragma unroll
            for (int nj = 0; nj < NJ; ++nj) {
                int n = bn + wc + nj * 16 + cc;
                float bv = bias[n];
#pragma unroll
                for (int r = 0; r < 4; ++r) {
                    int m = bm + wr + mi * 16 + 4 * g + r;
                    Cout[(size_t)m * Ndim + n] = acc[mi][nj][r] + bv;
                }
            }
    }
}

// ---------- fused causal attention (R8 structure + LDS-routed O epilogue) ----------
__global__ __launch_bounds__(256) void k_attn11(const uint16_t* __restrict__ Q,
                                                const uint16_t* __restrict__ K,
                                                const uint16_t* __restrict__ VT,
                                                float* __restrict__ attn,
                                                uint16_t* __restrict__ O,
                                                int* __restrict__ counters) {
    __shared__ uint16_t Kl[2][64 * 64];
    __shared__ uint16_t Vl[2][64 * 64];
    __shared__ uint16_t Pl[64 * 64];
    __shared__ int s_unit;
    int tid = threadIdx.x;
    int wave = tid >> 6, lane = tid & 63, g = lane >> 4, cc = lane & 15;
    int qx = blockIdx.x & 7;                 // XCD heuristic (round-robin dispatch)

    for (;;) {
        __syncthreads();
        if (tid == 0) s_unit = atomicAdd(&counters[qx], 1);
        __syncthreads();
        int u = s_unit;
        if (u >= 96) break;
        int qt = 31 - (u / 3);               // heaviest first
        int bh = qx * 3 + (u % 3);
        int qb = qt * 64, nt = qt + 1;
        const uint16_t* Qp = Q + (size_t)bh * 2048 * 64;
        const uint16_t* Kp = K + (size_t)bh * 2048 * 64;
        const uint16_t* Vp = VT + (size_t)bh * 64 * 2048;
        float* ap = attn + (size_t)bh * 2048 * 2048 + (size_t)qb * 2048;

        const uint16_t* qrp = Qp + (size_t)(qb + 16 * wave + cc) * 64 + g * 8;
        bf16x8 qa0 = *(const bf16x8*)qrp;
        bf16x8 qa1 = *(const bf16x8*)(qrp + 32);
        int myq = qb + 16 * wave + cc;
        int prow = 16 * wave + cc;

        // ---- pass 1: row sums (K-only) ----
        float lpart = 0.f;
        stage64_swz(Kp, 64, Kl[0], tid);
        asm volatile("s_waitcnt vmcnt(0)" ::: "memory");
        __builtin_amdgcn_s_barrier();
        int cur = 0;
        for (int ks = 0; ks < nt; ++ks) {
            if (ks + 1 < nt) stage64_swz(Kp + (size_t)(ks + 1) * 4096, 64, Kl[cur ^ 1], tid);
            __builtin_amdgcn_sched_barrier(0);
#pragma unroll
            for (int t = 0; t < 4; ++t) {
                bf16x8 k0 = ldsfrag(Kl[cur], t * 16 + cc, 0, g);
                bf16x8 k1 = ldsfrag(Kl[cur], t * 16 + cc, 1, g);
                f32x4 z = {0.f, 0.f, 0.f, 0.f};
                __builtin_amdgcn_s_setprio(1);
                z = __builtin_amdgcn_mfma_f32_16x16x32_bf16(k0, qa0, z, 0, 0, 0);
                z = __builtin_amdgcn_mfma_f32_16x16x32_bf16(k1, qa1, z, 0, 0, 0);
                __builtin_amdgcn_s_setprio(0);
#pragma unroll
                for (int r = 0; r < 4; ++r) {
                    int kabs = ks * 64 + t * 16 + 4 * g + r;
                    lpart += (kabs <= myq) ? __expf(z[r]) : 0.f;
                }
            }
            asm volatile("s_waitcnt vmcnt(0)" ::: "memory");
            __builtin_amdgcn_s_barrier();
            cur ^= 1;
        }
        lpart += __shfl_xor(lpart, 16, 64);
        lpart += __shfl_xor(lpart, 32, 64);
        float rinv = 1.0f / lpart;

        // ---- pass 2: P -> LDS -> PV, then full-line attn dump ----
        f32x4 Oa[4] = {};
        stage64_swz(Kp, 64, Kl[0], tid);
        stage64_swz(Vp, 2048, Vl[0], tid);
        asm volatile("s_waitcnt vmcnt(0)" ::: "memory");
        __builtin_amdgcn_s_barrier();
        cur = 0;
        for (int ks = 0; ks < nt; ++ks) {
            if (ks + 1 < nt) {
                stage64_swz(Kp + (size_t)(ks + 1) * 4096, 64, Kl[cur ^ 1], tid);
                stage64_swz(Vp + (size_t)(ks + 1) * 64, 2048, Vl[cur ^ 1], tid);
            }
            __builtin_amdgcn_sched_barrier(0);
#pragma unroll
            for (int t = 0; t < 4; ++t) {
                bf16x8 k0 = ldsfrag(Kl[cur], t * 16 + cc, 0, g);
                bf16x8 k1 = ldsfrag(Kl[cur], t * 16 + cc, 1, g);
                f32x4 z = {0.f, 0.f, 0.f, 0.f};
                __builtin_amdgcn_s_setprio(1);
                z = __builtin_amdgcn_mfma_f32_16x16x32_bf16(k0, qa0, z, 0, 0, 0);
                z = __builtin_amdgcn_mfma_f32_16x16x32_bf16(k1, qa1, z, 0, 0, 0);
                __builtin_amdgcn_s_setprio(0);
                bf16x4 pb;
#pragma unroll
                for (int r = 0; r < 4; ++r) {
                    int kabs = ks * 64 + t * 16 + 4 * g + r;
                    float p = (kabs <= myq) ? __expf(z[r]) * rinv : 0.f;
                    pb[r] = (__bf16)p;
                }
                *(bf16x4*)((char*)Pl + prow * 128 + ((t * 32 + 8 * g) ^ ((prow & 7) << 4))) = pb;
            }
            // P round-trip fence (wave-private rows; DS in-order per wave)
            asm volatile("s_waitcnt lgkmcnt(0)" ::: "memory");
            __builtin_amdgcn_sched_barrier(0);
            bf16x8 pa0 = ldsfrag(Pl, prow, 0, g);
            bf16x8 pa1 = ldsfrag(Pl, prow, 1, g);
            __builtin_amdgcn_s_setprio(1);
#pragma unroll
            for (int n = 0; n < 4; ++n) {
                bf16x8 v0 = ldsfrag(Vl[cur], n * 16 + cc, 0, g);
                bf16x8 v1 = ldsfrag(Vl[cur], n * 16 + cc, 1, g);
                Oa[n] = __builtin_amdgcn_mfma_f32_16x16x32_bf16(pa0, v0, Oa[n], 0, 0, 0);
                Oa[n] = __builtin_amdgcn_mfma_f32_16x16x32_bf16(pa1, v1, Oa[n], 0, 0, 0);
            }
            __builtin_amdgcn_s_setprio(0);
            // attn dump from Pl: per inst = 4 rows x 256B contiguous (full lines)
#pragma unroll
            for (int i = 0; i < 4; ++i) {
                int row = 16 * wave + i * 4 + (lane >> 4);
                int bcol = (lane & 15) * 8;
                u32x2 w = *(const u32x2*)((const char*)Pl + row * 128 + (bcol ^ ((row & 7) << 4)));
                union { uint32_t u; float f; } a0, a1, a2, a3;
                a0.u = w[0] << 16; a1.u = w[0] & 0xFFFF0000u;
                a2.u = w[1] << 16; a3.u = w[1] & 0xFFFF0000u;
                f32x4 ov = {a0.f, a1.f, a2.f, a3.f};
                *(f32x4*)(ap + (size_t)row * 2048 + ks * 64 + (lane & 15) * 4) = ov;
            }
            // counted wait: drains the 4 stage loads, attn stores stay in flight
            asm volatile("s_waitcnt vmcnt(4)" ::: "memory");
            __builtin_amdgcn_s_barrier();
            cur ^= 1;
        }

        // zero-fill upper triangle: 1KB-contiguous per wave-inst
        {
            f32x4 zz = {0.f, 0.f, 0.f, 0.f};
            int zb = nt * 64;
            for (int r = 0; r < 16; ++r) {
                float* zp = ap + (size_t)(16 * wave + r) * 2048;
                for (int c = zb + lane * 4; c < 2048; c += 256)
                    *(f32x4*)(zp + c) = zz;
            }
        }

        // ---- O epilogue routed through Pl (wave-private rows) -> 16B stores ----
        {
#pragma unroll
            for (int n = 0; n < 4; ++n)
#pragma unroll
                for (int r = 0; r < 4; ++r)
                    Pl[(16 * wave + 4 * g + r) * 64 + n * 16 + cc] = f2bf(Oa[n][r]);
            asm volatile("s_waitcnt lgkmcnt(0)" ::: "memory");
            __builtin_amdgcn_sched_barrier(0);
            int b = bh / 12, h = bh % 12;
#pragma unroll
            for (int i = 0; i < 2; ++i) {
                int chunkv = i * 64 + lane;
                int rl = chunkv >> 3;            // 0..15
                int c8 = (chunkv & 7) * 8;
                u16x8 v = *(const u16x8*)(Pl + (16 * wave + rl) * 64 + c8);
                *(u16x8*)(O + (size_t)(b * 2048 + qb + 16 * wave + rl) * 768 + h * 64 + c8) = v;
            }
        }
    }
}

// ---------- launcher ----------
extern "C" void kernel_launch(void* const* d_in, const int* in_sizes, int n_in,
                              void* d_out, int out_size, void* d_ws, size_t ws_size,
                              hipStream_t stream) {
    (void)in_sizes; (void)n_in; (void)out_size; (void)ws_size;
    const float* x    = (const float*)d_in[0];
    const float* Wqkv = (const float*)d_in[1];
    const float* bqkv = (const float*)d_in[2];
    const float* Wo   = (const float*)d_in[3];
    const float* bo   = (const float*)d_in[4];
    float* out  = (float*)d_out;
    float* attn = out + (size_t)4096 * 768;

    char* ws = (char*)d_ws;
    uint16_t* xbf   = (uint16_t*)(ws);             // 4096x768 bf16 (reused as Ow)
    uint16_t* WqkvT = (uint16_t*)(ws + 6291456);   // 2304x768 bf16
    uint16_t* WoT   = (uint16_t*)(ws + 9830400);   // 768x768 bf16
    uint16_t* Qw    = (uint16_t*)(ws + 11010048);  // [24][2048][64]
    uint16_t* Kw    = (uint16_t*)(ws + 17301504);  // [24][2048][64]
    uint16_t* VTw   = (uint16_t*)(ws + 29884416);  // [24][64][2048]
    int* counters   = (int*)(ws + 36175872);       // per-XCD work counters
    uint16_t* Ow    = xbf;                         // xbf dead after QKV GEMM

    k_prep<<<dim3(2112), 256, 0, stream>>>(x, xbf, Wqkv, WqkvT, Wo, WoT, counters);
    k_gemm<128, 128, 0><<<dim3(18, 32), 256, 0, stream>>>(xbf, WqkvT, bqkv, nullptr,
                                                          Qw, Kw, VTw, 2304, 768);
    k_attn11<<<dim3(1024), 256, 0, stream>>>(Qw, Kw, VTw, attn, Ow, counters);
    k_gemm<64, 128, 1><<<dim3(6, 64), 256, 0, stream>>>(Ow, WoT, bo, out,
                                                        nullptr, nullptr, nullptr, 768, 768);
}